// Round 1
// baseline (84.392 us; speedup 1.0000x reference)
//
#include <hip/hip_runtime.h>
#include <hip/hip_bf16.h>
#include <stdint.h>

#define TOKENS 4096
#define DIN 1024
#define DOUT 1024
#define RANK 8

typedef __attribute__((ext_vector_type(4))) float f32x4;
typedef __attribute__((ext_vector_type(8))) short short8;

__device__ __forceinline__ unsigned short f2bf(float f) {
    union { float f; unsigned u; } v; v.f = f;
    unsigned r = v.u + 0x7FFFu + ((v.u >> 16) & 1u);
    return (unsigned short)(r >> 16);
}

// W [DOUT][DIN] fp32 -> bf16
__global__ __launch_bounds__(256) void k_convert_w(const float* __restrict__ W,
                                                   ushort* __restrict__ Wb) {
    int i = blockIdx.x * 256 + threadIdx.x;
    float4 v = ((const float4*)W)[i];
    ushort4 u;
    u.x = f2bf(v.x); u.y = f2bf(v.y); u.z = f2bf(v.z); u.w = f2bf(v.w);
    ((ushort4*)Wb)[i] = u;
}

// Per token t: inter[t][r] = dot(x[t,:], B_params[t,r,:]); also emit x in bf16.
__global__ __launch_bounds__(256) void k_inter(const float* __restrict__ x,
                                               const float* __restrict__ Bp,
                                               float* __restrict__ inter,
                                               ushort* __restrict__ xb) {
    int t = blockIdx.x;
    int tid = threadIdx.x;
    int lane = tid & 63, wave = tid >> 6;

    const float4* x4 = (const float4*)(x + (size_t)t * DIN);
    float4 xv = x4[tid];

    ushort4 u;
    u.x = f2bf(xv.x); u.y = f2bf(xv.y); u.z = f2bf(xv.z); u.w = f2bf(xv.w);
    ((ushort4*)(xb + (size_t)t * DIN))[tid] = u;

    const float4* B4 = (const float4*)(Bp + (size_t)t * RANK * DIN);
    float acc[RANK];
#pragma unroll
    for (int r = 0; r < RANK; ++r) {
        float4 bv = B4[r * 256 + tid];
        acc[r] = xv.x * bv.x + xv.y * bv.y + xv.z * bv.z + xv.w * bv.w;
    }

    __shared__ float part[4][RANK];
#pragma unroll
    for (int r = 0; r < RANK; ++r) {
        float v = acc[r];
#pragma unroll
        for (int off = 32; off > 0; off >>= 1) v += __shfl_xor(v, off, 64);
        if (lane == 0) part[wave][r] = v;
    }
    __syncthreads();
    if (tid < RANK) {
        float s = part[0][tid] + part[1][tid] + part[2][tid] + part[3][tid];
        inter[(size_t)t * RANK + tid] = s;
    }
}

// C[m,o] = sum_k Xb[m,k]*Wb[o,k] (bf16 MFMA) + bias[o] + sum_r inter[m,r]*A[m,o,r]
// BM=64, BN=128, BK=64; 256 threads = 4 waves; wave w owns cols [w*32, w*32+32).
__global__ __launch_bounds__(256) void k_gemm(const ushort* __restrict__ Xb,
                                              const ushort* __restrict__ Wb,
                                              const float* __restrict__ bias,
                                              const float* __restrict__ inter,
                                              const float* __restrict__ Ap,
                                              float* __restrict__ out) {
    __shared__ ushort As[64 * 64];   // [m][k], k contiguous
    __shared__ ushort Bs[128 * 64];  // [o][k], k contiguous

    const int tid = threadIdx.x;
    const int lane = tid & 63, wave = tid >> 6;
    const int M0 = blockIdx.x * 64;
    const int N0 = blockIdx.y * 128;
    const int col16 = lane & 15;
    const int kg = lane >> 4;  // 0..3

    f32x4 acc[4][2] = {};

    for (int kt = 0; kt < DIN; kt += 64) {
        __syncthreads();
#pragma unroll
        for (int it = 0; it < 2; ++it) {
            int flat = it * 256 + tid;          // 0..511
            int row = flat >> 3, ch = flat & 7; // 64 rows x 8 chunks of 16B
            const ushort* g = Xb + (size_t)(M0 + row) * DIN + kt + ch * 8;
            __builtin_amdgcn_global_load_lds(
                (const __attribute__((address_space(1))) void*)g,
                (__attribute__((address_space(3))) void*)(As + flat * 8), 16, 0, 0);
        }
#pragma unroll
        for (int it = 0; it < 4; ++it) {
            int flat = it * 256 + tid;          // 0..1023
            int row = flat >> 3, ch = flat & 7; // 128 rows x 8 chunks
            const ushort* g = Wb + (size_t)(N0 + row) * DIN + kt + ch * 8;
            __builtin_amdgcn_global_load_lds(
                (const __attribute__((address_space(1))) void*)g,
                (__attribute__((address_space(3))) void*)(Bs + flat * 8), 16, 0, 0);
        }
        asm volatile("s_waitcnt vmcnt(0)" ::: "memory");
        __syncthreads();

#pragma unroll
        for (int ks = 0; ks < 2; ++ks) {
            short8 a[4], b[2];
#pragma unroll
            for (int mf = 0; mf < 4; ++mf)
                a[mf] = *(const short8*)(As + (mf * 16 + col16) * 64 + ks * 32 + kg * 8);
#pragma unroll
            for (int nf = 0; nf < 2; ++nf)
                b[nf] = *(const short8*)(Bs + (wave * 32 + nf * 16 + col16) * 64 + ks * 32 + kg * 8);
#pragma unroll
            for (int mf = 0; mf < 4; ++mf)
#pragma unroll
                for (int nf = 0; nf < 2; ++nf)
                    acc[mf][nf] = __builtin_amdgcn_mfma_f32_16x16x32_bf16(
                        a[mf], b[nf], acc[mf][nf], 0, 0, 0);
        }
    }

    // Epilogue: out[m,o] = acc + bias[o] + dot(inter[m,:], A[m,o,:])
#pragma unroll
    for (int nf = 0; nf < 2; ++nf) {
        int o = N0 + wave * 32 + nf * 16 + col16;
        float bb = bias[o];
#pragma unroll
        for (int mf = 0; mf < 4; ++mf) {
#pragma unroll
            for (int rg = 0; rg < 4; ++rg) {
                int m = M0 + mf * 16 + kg * 4 + rg;
                const float4* a8 = (const float4*)(Ap + ((size_t)m * DOUT + o) * RANK);
                const float4* iv = (const float4*)(inter + (size_t)m * RANK);
                float4 a0 = a8[0], a1 = a8[1];
                float4 i0 = iv[0], i1 = iv[1];
                float ad = a0.x * i0.x + a0.y * i0.y + a0.z * i0.z + a0.w * i0.w +
                           a1.x * i1.x + a1.y * i1.y + a1.z * i1.z + a1.w * i1.w;
                out[(size_t)m * DOUT + o] = acc[mf][nf][rg] + bb + ad;
            }
        }
    }
}

extern "C" void kernel_launch(void* const* d_in, const int* in_sizes, int n_in,
                              void* d_out, int out_size, void* d_ws, size_t ws_size,
                              hipStream_t stream) {
    const float* x    = (const float*)d_in[0];
    const float* Ap   = (const float*)d_in[1];
    const float* Bp   = (const float*)d_in[2];
    const float* W    = (const float*)d_in[3];
    const float* bias = (const float*)d_in[4];
    float* out = (float*)d_out;

    // ws layout: xb (8 MB) | Wb (2 MB) | inter (128 KB)  => ~10.6 MB
    ushort* xb = (ushort*)d_ws;
    ushort* Wb = xb + (size_t)TOKENS * DIN;
    float* inter = (float*)(Wb + (size_t)DOUT * DIN);

    hipLaunchKernelGGL(k_convert_w, dim3(DOUT * DIN / 1024), dim3(256), 0, stream, W, Wb);
    hipLaunchKernelGGL(k_inter, dim3(TOKENS), dim3(256), 0, stream, x, Bp, inter, xb);
    hipLaunchKernelGGL(k_gemm, dim3(TOKENS / 64, DOUT / 128), dim3(256), 0, stream,
                       xb, Wb, bias, inter, Ap, out);
}

// Round 2
// 82.607 us; speedup vs baseline: 1.0216x; 1.0216x over previous
//
#include <hip/hip_runtime.h>
#include <hip/hip_bf16.h>
#include <stdint.h>

#define TOKENS 4096
#define DIN 1024
#define DOUT 1024
#define RANK 8

typedef __attribute__((ext_vector_type(4))) float f32x4;
typedef __attribute__((ext_vector_type(8))) short short8;

__device__ __forceinline__ unsigned short f2bf(float f) {
    union { float f; unsigned u; } v; v.f = f;
    unsigned r = v.u + 0x7FFFu + ((v.u >> 16) & 1u);
    return (unsigned short)(r >> 16);
}

// W [DOUT][DIN] fp32 -> bf16
__global__ __launch_bounds__(256) void k_convert_w(const float* __restrict__ W,
                                                   ushort* __restrict__ Wb) {
    int i = blockIdx.x * 256 + threadIdx.x;
    float4 v = ((const float4*)W)[i];
    ushort4 u;
    u.x = f2bf(v.x); u.y = f2bf(v.y); u.z = f2bf(v.z); u.w = f2bf(v.w);
    ((ushort4*)Wb)[i] = u;
}

// One block per token t:
//   inter[r] = dot(x[t,:], B_params[t,r,:])        (in-register + LDS reduce)
//   out[t,o] = bias[o] + sum_r inter[r]*A[t,o,r]   (streams A_params once)
//   xb[t,:]  = bf16(x[t,:])                        (for the GEMM kernel)
// out is fully overwritten -> deterministic across graph replays.
__global__ __launch_bounds__(256) void k_lora(const float* __restrict__ x,
                                              const float* __restrict__ Bp,
                                              const float* __restrict__ Ap,
                                              const float* __restrict__ bias,
                                              float* __restrict__ out,
                                              ushort* __restrict__ xb) {
    const int t = blockIdx.x;
    const int tid = threadIdx.x;
    const int lane = tid & 63, wave = tid >> 6;

    float4 xv = ((const float4*)(x + (size_t)t * DIN))[tid];

    ushort4 u;
    u.x = f2bf(xv.x); u.y = f2bf(xv.y); u.z = f2bf(xv.z); u.w = f2bf(xv.w);
    ((ushort4*)(xb + (size_t)t * DIN))[tid] = u;

    const float4* B4 = (const float4*)(Bp + (size_t)t * RANK * DIN);
    float acc[RANK];
#pragma unroll
    for (int r = 0; r < RANK; ++r) {
        float4 bv = B4[r * 256 + tid];
        acc[r] = xv.x * bv.x + xv.y * bv.y + xv.z * bv.z + xv.w * bv.w;
    }

    __shared__ float part[4][RANK];
    __shared__ float sint[RANK];
#pragma unroll
    for (int r = 0; r < RANK; ++r) {
        float v = acc[r];
#pragma unroll
        for (int off = 32; off > 0; off >>= 1) v += __shfl_xor(v, off, 64);
        if (lane == 0) part[wave][r] = v;
    }
    __syncthreads();
    if (tid < RANK)
        sint[tid] = part[0][tid] + part[1][tid] + part[2][tid] + part[3][tid];
    __syncthreads();

    const float i0 = sint[0], i1 = sint[1], i2 = sint[2], i3 = sint[3];
    const float i4 = sint[4], i5 = sint[5], i6 = sint[6], i7 = sint[7];

    // Thread owns 4 contiguous outputs -> 128B contiguous A_params read,
    // float4 out/bias accesses.
    const float4* A4 = (const float4*)(Ap + ((size_t)t * DOUT + tid * 4) * RANK);
    float res[4];
#pragma unroll
    for (int j = 0; j < 4; ++j) {
        float4 a0 = A4[j * 2], a1 = A4[j * 2 + 1];
        res[j] = a0.x * i0 + a0.y * i1 + a0.z * i2 + a0.w * i3 +
                 a1.x * i4 + a1.y * i5 + a1.z * i6 + a1.w * i7;
    }
    float4 bb = ((const float4*)bias)[tid];
    float4 o4;
    o4.x = res[0] + bb.x; o4.y = res[1] + bb.y;
    o4.z = res[2] + bb.z; o4.w = res[3] + bb.w;
    ((float4*)(out + (size_t)t * DOUT))[tid] = o4;
}

// out[m,o] += sum_k Xb[m,k]*Wb[o,k]  (bf16 MFMA, BM=128 BN=64 BK=64,
// 4 waves in 2x2, each wave a 64x32 quadrant = 4x2 16x16 frags)
__global__ __launch_bounds__(256) void k_gemm_add(const ushort* __restrict__ Xb,
                                                  const ushort* __restrict__ Wb,
                                                  float* __restrict__ out) {
    __shared__ ushort As[128 * 64];  // [m][k]
    __shared__ ushort Bs[64 * 64];   // [o][k]

    const int tid = threadIdx.x;
    const int lane = tid & 63, wave = tid >> 6;
    const int wm = wave >> 1, wn = wave & 1;
    const int M0 = blockIdx.y * 128;
    const int N0 = blockIdx.x * 64;
    const int col16 = lane & 15;
    const int kg = lane >> 4;

    f32x4 acc[4][2] = {};

    for (int kt = 0; kt < DIN; kt += 64) {
        __syncthreads();
#pragma unroll
        for (int it = 0; it < 4; ++it) {
            int flat = it * 256 + tid;           // 0..1023 : 128 rows x 8 chunks
            int row = flat >> 3, ch = flat & 7;
            const ushort* g = Xb + (size_t)(M0 + row) * DIN + kt + ch * 8;
            __builtin_amdgcn_global_load_lds(
                (const __attribute__((address_space(1))) void*)g,
                (__attribute__((address_space(3))) void*)(As + flat * 8), 16, 0, 0);
        }
#pragma unroll
        for (int it = 0; it < 2; ++it) {
            int flat = it * 256 + tid;           // 0..511 : 64 rows x 8 chunks
            int row = flat >> 3, ch = flat & 7;
            const ushort* g = Wb + (size_t)(N0 + row) * DIN + kt + ch * 8;
            __builtin_amdgcn_global_load_lds(
                (const __attribute__((address_space(1))) void*)g,
                (__attribute__((address_space(3))) void*)(Bs + flat * 8), 16, 0, 0);
        }
        asm volatile("s_waitcnt vmcnt(0)" ::: "memory");
        __syncthreads();

#pragma unroll
        for (int ks = 0; ks < 2; ++ks) {
            short8 a[4], b[2];
#pragma unroll
            for (int mf = 0; mf < 4; ++mf)
                a[mf] = *(const short8*)(As + (wm * 64 + mf * 16 + col16) * 64 + ks * 32 + kg * 8);
#pragma unroll
            for (int nf = 0; nf < 2; ++nf)
                b[nf] = *(const short8*)(Bs + (wn * 32 + nf * 16 + col16) * 64 + ks * 32 + kg * 8);
#pragma unroll
            for (int mf = 0; mf < 4; ++mf)
#pragma unroll
                for (int nf = 0; nf < 2; ++nf)
                    acc[mf][nf] = __builtin_amdgcn_mfma_f32_16x16x32_bf16(
                        a[mf], b[nf], acc[mf][nf], 0, 0, 0);
        }
    }

#pragma unroll
    for (int nf = 0; nf < 2; ++nf) {
        int o = N0 + wn * 32 + nf * 16 + col16;
#pragma unroll
        for (int mf = 0; mf < 4; ++mf) {
#pragma unroll
            for (int rg = 0; rg < 4; ++rg) {
                int m = M0 + wm * 64 + mf * 16 + kg * 4 + rg;
                size_t idx = (size_t)m * DOUT + o;
                out[idx] += acc[mf][nf][rg];
            }
        }
    }
}

extern "C" void kernel_launch(void* const* d_in, const int* in_sizes, int n_in,
                              void* d_out, int out_size, void* d_ws, size_t ws_size,
                              hipStream_t stream) {
    const float* x    = (const float*)d_in[0];
    const float* Ap   = (const float*)d_in[1];
    const float* Bp   = (const float*)d_in[2];
    const float* W    = (const float*)d_in[3];
    const float* bias = (const float*)d_in[4];
    float* out = (float*)d_out;

    // ws layout: xb (8 MB bf16 x) | Wb (2 MB bf16 W)
    ushort* xb = (ushort*)d_ws;
    ushort* Wb = xb + (size_t)TOKENS * DIN;

    hipLaunchKernelGGL(k_convert_w, dim3(DOUT * DIN / 1024), dim3(256), 0, stream, W, Wb);
    hipLaunchKernelGGL(k_lora, dim3(TOKENS), dim3(256), 0, stream,
                       x, Bp, Ap, bias, out, xb);
    hipLaunchKernelGGL(k_gemm_add, dim3(DOUT / 64, TOKENS / 128), dim3(256), 0, stream,
                       xb, Wb, out);
}

// Round 3
// 81.428 us; speedup vs baseline: 1.0364x; 1.0145x over previous
//
#include <hip/hip_runtime.h>
#include <hip/hip_bf16.h>
#include <stdint.h>

#define TOKENS 4096
#define DIN 1024
#define DOUT 1024
#define RANK 8

typedef __attribute__((ext_vector_type(4))) float f32x4;
typedef __attribute__((ext_vector_type(8))) short short8;

__device__ __forceinline__ unsigned short f2bf(float f) {
    union { float f; unsigned u; } v; v.f = f;
    unsigned r = v.u + 0x7FFFu + ((v.u >> 16) & 1u);
    return (unsigned short)(r >> 16);
}

// W [DOUT][DIN] fp32 -> bf16
__global__ __launch_bounds__(256) void k_convert_w(const float* __restrict__ W,
                                                   ushort* __restrict__ Wb) {
    int i = blockIdx.x * 256 + threadIdx.x;
    float4 v = ((const float4*)W)[i];
    ushort4 u;
    u.x = f2bf(v.x); u.y = f2bf(v.y); u.z = f2bf(v.z); u.w = f2bf(v.w);
    ((ushort4*)Wb)[i] = u;
}

// One block per token t:
//   inter[r] = dot(x[t,:], B_params[t,r,:])
//   out[t,o] = bias[o] + sum_r inter[r]*A[t,o,r]
//   xb[t,:]  = bf16(x[t,:])
// ALL global accesses are lane-contiguous float4:
//   A_params is read flat (f = j*256+tid); each float4 is half a row
//   (h = tid&1), combined across the lane pair with shfl_xor(1), row sums
//   staged through 4KB LDS so the out-store is a coalesced float4.
__global__ __launch_bounds__(256) void k_lora(const float* __restrict__ x,
                                              const float* __restrict__ Bp,
                                              const float* __restrict__ Ap,
                                              const float* __restrict__ bias,
                                              float* __restrict__ out,
                                              ushort* __restrict__ xb) {
    const int t = blockIdx.x;
    const int tid = threadIdx.x;
    const int lane = tid & 63, wave = tid >> 6;

    float4 xv = ((const float4*)(x + (size_t)t * DIN))[tid];

    ushort4 u;
    u.x = f2bf(xv.x); u.y = f2bf(xv.y); u.z = f2bf(xv.z); u.w = f2bf(xv.w);
    ((ushort4*)(xb + (size_t)t * DIN))[tid] = u;

    // ---- inter[r] = dot(x, B[r,:]) ----
    const float4* B4 = (const float4*)(Bp + (size_t)t * RANK * DIN);
    float acc[RANK];
#pragma unroll
    for (int r = 0; r < RANK; ++r) {
        float4 bv = B4[r * 256 + tid];
        acc[r] = xv.x * bv.x + xv.y * bv.y + xv.z * bv.z + xv.w * bv.w;
    }

    __shared__ float part[4][RANK];
    __shared__ float sint[RANK];
    __shared__ float sums[DOUT];
#pragma unroll
    for (int r = 0; r < RANK; ++r) {
        float v = acc[r];
#pragma unroll
        for (int off = 32; off > 0; off >>= 1) v += __shfl_xor(v, off, 64);
        if (lane == 0) part[wave][r] = v;
    }
    __syncthreads();
    if (tid < RANK)
        sint[tid] = part[0][tid] + part[1][tid] + part[2][tid] + part[3][tid];
    __syncthreads();

    // ---- adaptation: flat-coalesced A read ----
    // lane parity selects which half of inter this thread's float4 dots with
    float4 ih;
    if (tid & 1) { ih.x = sint[4]; ih.y = sint[5]; ih.z = sint[6]; ih.w = sint[7]; }
    else         { ih.x = sint[0]; ih.y = sint[1]; ih.z = sint[2]; ih.w = sint[3]; }

    const float4* A4 = (const float4*)(Ap + (size_t)t * DOUT * RANK);
#pragma unroll
    for (int j = 0; j < 8; ++j) {
        float4 v = A4[j * 256 + tid];
        float p = v.x * ih.x + v.y * ih.y + v.z * ih.z + v.w * ih.w;
        p += __shfl_xor(p, 1, 64);           // combine halves of row o
        if (!(tid & 1)) sums[j * 128 + (tid >> 1)] = p;  // 32 lanes -> 32 banks
    }
    __syncthreads();

    float4 s4 = ((const float4*)sums)[tid];
    float4 bb = ((const float4*)bias)[tid];
    float4 o4;
    o4.x = s4.x + bb.x; o4.y = s4.y + bb.y;
    o4.z = s4.z + bb.z; o4.w = s4.w + bb.w;
    ((float4*)(out + (size_t)t * DOUT))[tid] = o4;
}

// out[m,o] += sum_k Xb[m,k]*Wb[o,k]  (bf16 MFMA, BM=128 BN=64 BK=64)
__global__ __launch_bounds__(256) void k_gemm_add(const ushort* __restrict__ Xb,
                                                  const ushort* __restrict__ Wb,
                                                  float* __restrict__ out) {
    __shared__ ushort As[128 * 64];  // [m][k]
    __shared__ ushort Bs[64 * 64];   // [o][k]

    const int tid = threadIdx.x;
    const int lane = tid & 63, wave = tid >> 6;
    const int wm = wave >> 1, wn = wave & 1;
    const int M0 = blockIdx.y * 128;
    const int N0 = blockIdx.x * 64;
    const int col16 = lane & 15;
    const int kg = lane >> 4;

    f32x4 acc[4][2] = {};

    for (int kt = 0; kt < DIN; kt += 64) {
        __syncthreads();
#pragma unroll
        for (int it = 0; it < 4; ++it) {
            int flat = it * 256 + tid;
            int row = flat >> 3, ch = flat & 7;
            const ushort* g = Xb + (size_t)(M0 + row) * DIN + kt + ch * 8;
            __builtin_amdgcn_global_load_lds(
                (const __attribute__((address_space(1))) void*)g,
                (__attribute__((address_space(3))) void*)(As + flat * 8), 16, 0, 0);
        }
#pragma unroll
        for (int it = 0; it < 2; ++it) {
            int flat = it * 256 + tid;
            int row = flat >> 3, ch = flat & 7;
            const ushort* g = Wb + (size_t)(N0 + row) * DIN + kt + ch * 8;
            __builtin_amdgcn_global_load_lds(
                (const __attribute__((address_space(1))) void*)g,
                (__attribute__((address_space(3))) void*)(Bs + flat * 8), 16, 0, 0);
        }
        asm volatile("s_waitcnt vmcnt(0)" ::: "memory");
        __syncthreads();

#pragma unroll
        for (int ks = 0; ks < 2; ++ks) {
            short8 a[4], b[2];
#pragma unroll
            for (int mf = 0; mf < 4; ++mf)
                a[mf] = *(const short8*)(As + (wm * 64 + mf * 16 + col16) * 64 + ks * 32 + kg * 8);
#pragma unroll
            for (int nf = 0; nf < 2; ++nf)
                b[nf] = *(const short8*)(Bs + (wn * 32 + nf * 16 + col16) * 64 + ks * 32 + kg * 8);
#pragma unroll
            for (int mf = 0; mf < 4; ++mf)
#pragma unroll
                for (int nf = 0; nf < 2; ++nf)
                    acc[mf][nf] = __builtin_amdgcn_mfma_f32_16x16x32_bf16(
                        a[mf], b[nf], acc[mf][nf], 0, 0, 0);
        }
    }

#pragma unroll
    for (int nf = 0; nf < 2; ++nf) {
        int o = N0 + wn * 32 + nf * 16 + col16;
#pragma unroll
        for (int mf = 0; mf < 4; ++mf) {
#pragma unroll
            for (int rg = 0; rg < 4; ++rg) {
                int m = M0 + wm * 64 + mf * 16 + kg * 4 + rg;
                size_t idx = (size_t)m * DOUT + o;
                out[idx] += acc[mf][nf][rg];
            }
        }
    }
}

extern "C" void kernel_launch(void* const* d_in, const int* in_sizes, int n_in,
                              void* d_out, int out_size, void* d_ws, size_t ws_size,
                              hipStream_t stream) {
    const float* x    = (const float*)d_in[0];
    const float* Ap   = (const float*)d_in[1];
    const float* Bp   = (const float*)d_in[2];
    const float* W    = (const float*)d_in[3];
    const float* bias = (const float*)d_in[4];
    float* out = (float*)d_out;

    ushort* xb = (ushort*)d_ws;
    ushort* Wb = xb + (size_t)TOKENS * DIN;

    hipLaunchKernelGGL(k_convert_w, dim3(DOUT * DIN / 1024), dim3(256), 0, stream, W, Wb);
    hipLaunchKernelGGL(k_lora, dim3(TOKENS), dim3(256), 0, stream,
                       x, Bp, Ap, bias, out, xb);
    hipLaunchKernelGGL(k_gemm_add, dim3(DOUT / 64, TOKENS / 128), dim3(256), 0, stream,
                       xb, Wb, out);
}